// Round 16
// baseline (355.810 us; speedup 1.0000x reference)
//
#include <hip/hip_runtime.h>
#include <hip/hip_bf16.h>
#include <math.h>

// Problem constants (from setup_inputs / reference)
#define CLASSES     5
#define C_DIM       64
#define HW          441            // 21*21
#define B_ANCH      32
#define NSUP        25             // L*S support images
#define NROWS       (B_ANCH*HW)    // 14112 query rows
#define MSUP        (NSUP*HW)      // 11025 support descriptors
#define PER_CLS     (MSUP/CLASSES) // 2205 per class
#define TILE_COLS   32
#define ROW_BYTES   (C_DIM*2)      // 128 B per bf16 descriptor row
#define TILE_BYTES  (TILE_COLS*ROW_BYTES)   // 4 KB
#define PER_CLS_PAD 2304           // 72 tiles of 32
#define NPAD        (PER_CLS_PAD - PER_CLS) // 99 zero-filled pad rows/class
#define QUARTERS    4              // column splits per class (grid.y = 5*4)
#define TILES_PER_Q 18             // 18 tiles of 32 cols = 576 cols/quarter
#define ROWS_PER_BLK 128           // 4 waves x 32 rows (M_rep=2)
#define NBLK_X      ((NROWS + ROWS_PER_BLK - 1) / ROWS_PER_BLK)  // 111

#define NEG_INF  (-1e30f)

typedef __bf16 bf16x8 __attribute__((ext_vector_type(8)));
typedef float  f32x4  __attribute__((ext_vector_type(4)));

#define TOP3_INS(v, t0, t1, t2) do {                              \
    float _v = (v);                                               \
    float _n0 = fmaxf(_v, (t0));                                  \
    float _n1 = __builtin_amdgcn_fmed3f(_v, (t0), (t1));          \
    float _n2 = __builtin_amdgcn_fmed3f(_v, (t1), (t2));          \
    (t0) = _n0; (t1) = _n1; (t2) = _n2; } while (0)

#define TRIPLE_MERGE(u0, u1, u2, v0, v1, v2) do {                 \
    float _A = fminf((u0), (v0));                                 \
    float _B = fmaxf((u1), (v1));                                 \
    float _E = fmaxf((u2), (v2));                                 \
    float _m0 = fmaxf((u0), (v0));                                \
    float _m1 = __builtin_amdgcn_fmed3f((u0), (v0), _B);          \
    float _m2 = __builtin_amdgcn_fmed3f(_A, _B, _E);              \
    (u0) = _m0; (u1) = _m1; (u2) = _m2; } while (0)

typedef __attribute__((address_space(1))) const void g_void;
typedef __attribute__((address_space(3))) void l_void;
__device__ __forceinline__ void gload_lds16(const void* g, void* l) {
    __builtin_amdgcn_global_load_lds((g_void*)g, (l_void*)l, 16, 0, 0);
}
#define MFMA16(A, B, C) __builtin_amdgcn_mfma_f32_16x16x32_bf16((A), (B), (C), 0, 0, 0)

__device__ __forceinline__ void keep(float x) { asm volatile("" :: "v"(x)); }
__device__ __forceinline__ void keepv(const bf16x8& v) {
    const f32x4& f = reinterpret_cast<const f32x4&>(v);
    asm volatile("" :: "v"(f[0]), "v"(f[1]), "v"(f[2]), "v"(f[3]));
}

// ---------------------------------------------------------------------------
// Kernel 1: L2-normalize all rows (support + anchor) into row-major bf16.
// ---------------------------------------------------------------------------
__global__ __launch_bounds__(256) void norm_rows_kernel(
    const float* __restrict__ anchor, const float* __restrict__ support,
    __bf16* __restrict__ qb, __bf16* __restrict__ sb) {
    int r = blockIdx.x * 256 + threadIdx.x;
    const int total_main = MSUP + NROWS;
    if (r >= total_main) {
        int i = r - total_main;                    // pad-row zero fill
        if (i < CLASSES * NPAD) {
            int cls = i / NPAD, ix = PER_CLS + i % NPAD;
            __bf16* op = sb + ((size_t)cls * PER_CLS_PAD + ix) * C_DIM;
            bf16x8 z = {};
            #pragma unroll
            for (int c0 = 0; c0 < C_DIM; c0 += 8) *(bf16x8*)(op + c0) = z;
        }
        return;
    }
    bool isSup = r < MSUP;
    int rc = isSup ? r : r - MSUP;
    const float* in = isSup ? support : anchor;
    int img = rc / HW, p = rc % HW;
    const float* base = in + (size_t)img * C_DIM * HW + p;
    float q[C_DIM];
    float ss = 0.f;
    #pragma unroll
    for (int c = 0; c < C_DIM; ++c) { q[c] = base[c * HW]; ss += q[c] * q[c]; }
    float sc = rsqrtf(ss);
    __bf16* op;
    if (isSup) {
        int cls = rc / PER_CLS, ix = rc - cls * PER_CLS;
        op = sb + ((size_t)cls * PER_CLS_PAD + ix) * C_DIM;
    } else {
        op = qb + (size_t)rc * C_DIM;
    }
    #pragma unroll
    for (int c0 = 0; c0 < C_DIM; c0 += 8) {
        bf16x8 v;
        #pragma unroll
        for (int j = 0; j < 8; ++j) v[j] = (__bf16)(q[c0 + j] * sc);
        *(bf16x8*)(op + c0) = v;
    }
}

// ---------------------------------------------------------------------------
// CONTROL inner loop — exact round-15 structure (validated, absmax 0).
// Contiguous staging + XOR-swizzled LDS reads; 3 buffers; counted vmcnt(1).
// ---------------------------------------------------------------------------
template<int QNT, bool TAIL>
__device__ __forceinline__ void gemm_quarter(
    const char* stage_src, char* smem_base, const char* pB,
    int xoff0, int xoff1, int stage_dst_off, int lane, int lr,
    const bf16x8 a0[2], const bf16x8 a1[2],
    float t0[2][4], float t1[2][4], float t2[2][4]) {

    auto stage = [&](int buf, int tt) {
        gload_lds16(stage_src + tt * TILE_BYTES,
                    smem_base + buf * 4096 + stage_dst_off);
    };
    const f32x4 z = {0.f, 0.f, 0.f, 0.f};
    stage(0, 0);
    stage(1, 1);
    #pragma unroll
    for (int tt = 0; tt < QNT; ++tt) {
        if (tt < QNT - 1) asm volatile("s_waitcnt vmcnt(1)" ::: "memory");
        else              asm volatile("s_waitcnt vmcnt(0)" ::: "memory");
        __builtin_amdgcn_s_barrier();
        if (tt + 2 < QNT) stage((tt + 2) % 3, tt + 2);
        const int buf = tt % 3;
        const bool tail = TAIL && (tt == QNT - 1);
        const char* pb = pB + buf * 4096;
        bf16x8 b0 = *(const bf16x8*)(pb + xoff0);
        bf16x8 b1 = *(const bf16x8*)(pb + xoff1);
        bf16x8 b2 = *(const bf16x8*)(pb + 2048 + xoff0);
        bf16x8 b3 = *(const bf16x8*)(pb + 2048 + xoff1);
        f32x4 acc0, acc1, acc2, acc3;
        __builtin_amdgcn_s_setprio(1);
        acc0 = MFMA16(a0[0], b0, z); acc0 = MFMA16(a1[0], b1, acc0);
        acc1 = MFMA16(a0[1], b0, z); acc1 = MFMA16(a1[1], b1, acc1);
        acc2 = MFMA16(a0[0], b2, z); acc2 = MFMA16(a1[0], b3, acc2);
        acc3 = MFMA16(a0[1], b2, z); acc3 = MFMA16(a1[1], b3, acc3);
        __builtin_amdgcn_s_setprio(0);
        if (!tail) {
            #pragma unroll
            for (int j = 0; j < 4; ++j) {
                TOP3_INS(acc0[j], t0[0][j], t1[0][j], t2[0][j]);
                TOP3_INS(acc1[j], t0[1][j], t1[1][j], t2[1][j]);
                TOP3_INS(acc2[j], t0[0][j], t1[0][j], t2[0][j]);
                TOP3_INS(acc3[j], t0[1][j], t1[1][j], t2[1][j]);
            }
        } else {
            bool valid = lr < 13;
            #pragma unroll
            for (int j = 0; j < 4; ++j) {
                TOP3_INS(acc0[j], t0[0][j], t1[0][j], t2[0][j]);
                TOP3_INS(acc1[j], t0[1][j], t1[1][j], t2[1][j]);
                float v2 = valid ? acc2[j] : NEG_INF;
                float v3 = valid ? acc3[j] : NEG_INF;
                TOP3_INS(v2, t0[0][j], t1[0][j], t2[0][j]);
                TOP3_INS(v3, t0[1][j], t1[1][j], t2[1][j]);
            }
        }
    }
}

// common per-block setup shared by control and ablations
struct Setup {
    int lane, w, lr, kg, cls, q, rowbase;
    const char* stage_src;
    const char* pB;
    int xoff0, xoff1, sdst;
    bf16x8 a0[2], a1[2];
};
__device__ __forceinline__ Setup make_setup(
    const __bf16* qb, const __bf16* sb, char* smem) {
    Setup s;
    s.lane = threadIdx.x & 63;
    s.w    = threadIdx.x >> 6;
    s.lr   = s.lane & 15;
    s.kg   = s.lane >> 4;
    s.cls  = blockIdx.y >> 2;
    s.q    = blockIdx.y & 3;
    s.rowbase = blockIdx.x * ROWS_PER_BLK + s.w * 32;
    #pragma unroll
    for (int r = 0; r < 2; ++r) {
        int arow = s.rowbase + r * 16 + s.lr;
        int arc  = arow < NROWS ? arow : NROWS - 1;
        const bf16x8* qrow = (const bf16x8*)(qb + (size_t)arc * C_DIM);
        s.a0[r] = qrow[s.kg];
        s.a1[r] = qrow[4 + s.kg];
    }
    int srow = s.lane >> 3;
    int sgrn = (s.lane & 7) ^ (srow & 7);
    int srcSwz = srow * 128 + sgrn * 16;
    const char* qbase = (const char*)sb
        + (size_t)s.cls * PER_CLS_PAD * ROW_BYTES
        + (size_t)s.q * TILES_PER_Q * TILE_BYTES;
    s.stage_src = qbase + s.w * 1024 + srcSwz;
    s.xoff0 = (((s.lr & 7) ^ s.kg) << 4);
    s.xoff1 = s.xoff0 ^ 0x40;
    s.pB = (const char*)smem + s.lr * 128;
    s.sdst = s.w * 1024;
    return s;
}

// ---------------------------------------------------------------------------
// Kernel 2 (CONTROL): exact round-15 kernel, correct output.
// ---------------------------------------------------------------------------
__global__ __launch_bounds__(256, 4) void knn_mfma_kernel(
    const __bf16* __restrict__ qb, const __bf16* __restrict__ sb,
    float* __restrict__ part) {
    __shared__ char smem[3][4096];
    Setup s = make_setup(qb, sb, (char*)smem);
    float t0[2][4], t1[2][4], t2[2][4];
    #pragma unroll
    for (int r = 0; r < 2; ++r)
        #pragma unroll
        for (int j = 0; j < 4; ++j) {
            t0[r][j] = NEG_INF; t1[r][j] = NEG_INF; t2[r][j] = NEG_INF;
        }
    if (s.q == 3)
        gemm_quarter<15, true >(s.stage_src, (char*)smem, s.pB, s.xoff0,
                                s.xoff1, s.sdst, s.lane, s.lr, s.a0, s.a1,
                                t0, t1, t2);
    else
        gemm_quarter<18, false>(s.stage_src, (char*)smem, s.pB, s.xoff0,
                                s.xoff1, s.sdst, s.lane, s.lr, s.a0, s.a1,
                                t0, t1, t2);
    #pragma unroll
    for (int r = 0; r < 2; ++r) {
        #pragma unroll
        for (int j = 0; j < 4; ++j) {
            float u0 = t0[r][j], u1 = t1[r][j], u2 = t2[r][j];
            #pragma unroll
            for (int off = 1; off < 16; off <<= 1) {
                float v0 = __shfl_xor(u0, off, 64);
                float v1 = __shfl_xor(u1, off, 64);
                float v2 = __shfl_xor(u2, off, 64);
                TRIPLE_MERGE(u0, u1, u2, v0, v1, v2);
            }
            int row = s.rowbase + r * 16 + s.kg * 4 + j;
            if (s.lr == 0 && row < NROWS) {
                float* pp = part +
                    ((size_t)(row * CLASSES + s.cls) * QUARTERS + s.q) * 3;
                pp[0] = u0; pp[1] = u1; pp[2] = u2;
            }
        }
    }
}

// ---------------------------------------------------------------------------
// ABLATIONS: x4 internal repeat so each lands in the top-5 table.
// All share grid/block/LDS/launch_bounds with the control; tokens to scratch.
// ---------------------------------------------------------------------------
#define ABL_QNT(sq) ((sq).q == 3 ? 15 : 18)

// A: skeleton — stage + vmcnt + barrier + ds_read; no MFMA/TOP3/epilogue.
__global__ __launch_bounds__(256, 4) void abl_skel_kernel(
    const __bf16* __restrict__ qb, const __bf16* __restrict__ sb,
    float* __restrict__ scratch) {
    __shared__ char smem[3][4096];
    Setup s = make_setup(qb, sb, (char*)smem);
    const int QNT = ABL_QNT(s);
    #pragma unroll 1
    for (int rep = 0; rep < 4; ++rep) {
        gload_lds16(s.stage_src, (char*)smem + s.sdst);
        gload_lds16(s.stage_src + TILE_BYTES, (char*)smem + 4096 + s.sdst);
        #pragma unroll 1
        for (int tt = 0; tt < QNT; ++tt) {
            if (tt < QNT - 1) asm volatile("s_waitcnt vmcnt(1)" ::: "memory");
            else              asm volatile("s_waitcnt vmcnt(0)" ::: "memory");
            __builtin_amdgcn_s_barrier();
            if (tt + 2 < QNT) {
                int pbuf = tt + 2; while (pbuf >= 3) pbuf -= 3;
                gload_lds16(s.stage_src + (tt + 2) * TILE_BYTES,
                            (char*)smem + pbuf * 4096 + s.sdst);
            }
            int buf = tt; while (buf >= 3) buf -= 3;
            const char* pb = s.pB + buf * 4096;
            bf16x8 b0 = *(const bf16x8*)(pb + s.xoff0);
            bf16x8 b1 = *(const bf16x8*)(pb + s.xoff1);
            bf16x8 b2 = *(const bf16x8*)(pb + 2048 + s.xoff0);
            bf16x8 b3 = *(const bf16x8*)(pb + 2048 + s.xoff1);
            keepv(b0); keepv(b1); keepv(b2); keepv(b3);
        }
    }
    if (threadIdx.x == 0)
        scratch[blockIdx.x + NBLK_X * blockIdx.y] = 1.0f;
}

// B: no-sync — stage 2 buffers once; pure ds_read->MFMA->TOP3, no barriers.
__global__ __launch_bounds__(256, 4) void abl_nosync_kernel(
    const __bf16* __restrict__ qb, const __bf16* __restrict__ sb,
    float* __restrict__ scratch) {
    __shared__ char smem[3][4096];
    Setup s = make_setup(qb, sb, (char*)smem);
    const int QNT = ABL_QNT(s);
    float t0[2][4], t1[2][4], t2[2][4];
    #pragma unroll
    for (int r = 0; r < 2; ++r)
        #pragma unroll
        for (int j = 0; j < 4; ++j) {
            t0[r][j] = NEG_INF; t1[r][j] = NEG_INF; t2[r][j] = NEG_INF;
        }
    gload_lds16(s.stage_src, (char*)smem + s.sdst);
    gload_lds16(s.stage_src + TILE_BYTES, (char*)smem + 4096 + s.sdst);
    asm volatile("s_waitcnt vmcnt(0)" ::: "memory");
    __builtin_amdgcn_s_barrier();
    const f32x4 z = {0.f, 0.f, 0.f, 0.f};
    #pragma unroll 1
    for (int it = 0; it < 4 * 18; ++it) {     // 4 reps x 18 tiles (data reused)
        if (it >= 4 * QNT) break;
        const char* pb = s.pB + (it & 1) * 4096;
        bf16x8 b0 = *(const bf16x8*)(pb + s.xoff0);
        bf16x8 b1 = *(const bf16x8*)(pb + s.xoff1);
        bf16x8 b2 = *(const bf16x8*)(pb + 2048 + s.xoff0);
        bf16x8 b3 = *(const bf16x8*)(pb + 2048 + s.xoff1);
        f32x4 acc0, acc1, acc2, acc3;
        __builtin_amdgcn_s_setprio(1);
        acc0 = MFMA16(s.a0[0], b0, z); acc0 = MFMA16(s.a1[0], b1, acc0);
        acc1 = MFMA16(s.a0[1], b0, z); acc1 = MFMA16(s.a1[1], b1, acc1);
        acc2 = MFMA16(s.a0[0], b2, z); acc2 = MFMA16(s.a1[0], b3, acc2);
        acc3 = MFMA16(s.a0[1], b2, z); acc3 = MFMA16(s.a1[1], b3, acc3);
        __builtin_amdgcn_s_setprio(0);
        #pragma unroll
        for (int j = 0; j < 4; ++j) {
            TOP3_INS(acc0[j], t0[0][j], t1[0][j], t2[0][j]);
            TOP3_INS(acc1[j], t0[1][j], t1[1][j], t2[1][j]);
            TOP3_INS(acc2[j], t0[0][j], t1[0][j], t2[0][j]);
            TOP3_INS(acc3[j], t0[1][j], t1[1][j], t2[1][j]);
        }
    }
    #pragma unroll
    for (int r = 0; r < 2; ++r)
        #pragma unroll
        for (int j = 0; j < 4; ++j) {
            keep(t0[r][j]); keep(t1[r][j]); keep(t2[r][j]);
        }
    if (threadIdx.x == 0)
        scratch[blockIdx.x + NBLK_X * blockIdx.y] = 1.0f;
}

// C: no-MFMA — full rhythm; TOP3 fed directly from b-register bits.
__global__ __launch_bounds__(256, 4) void abl_nomfma_kernel(
    const __bf16* __restrict__ qb, const __bf16* __restrict__ sb,
    float* __restrict__ scratch) {
    __shared__ char smem[3][4096];
    Setup s = make_setup(qb, sb, (char*)smem);
    const int QNT = ABL_QNT(s);
    float t0[2][4], t1[2][4], t2[2][4];
    #pragma unroll
    for (int r = 0; r < 2; ++r)
        #pragma unroll
        for (int j = 0; j < 4; ++j) {
            t0[r][j] = NEG_INF; t1[r][j] = NEG_INF; t2[r][j] = NEG_INF;
        }
    #pragma unroll 1
    for (int rep = 0; rep < 4; ++rep) {
        gload_lds16(s.stage_src, (char*)smem + s.sdst);
        gload_lds16(s.stage_src + TILE_BYTES, (char*)smem + 4096 + s.sdst);
        #pragma unroll 1
        for (int tt = 0; tt < QNT; ++tt) {
            if (tt < QNT - 1) asm volatile("s_waitcnt vmcnt(1)" ::: "memory");
            else              asm volatile("s_waitcnt vmcnt(0)" ::: "memory");
            __builtin_amdgcn_s_barrier();
            if (tt + 2 < QNT) {
                int pbuf = tt + 2; while (pbuf >= 3) pbuf -= 3;
                gload_lds16(s.stage_src + (tt + 2) * TILE_BYTES,
                            (char*)smem + pbuf * 4096 + s.sdst);
            }
            int buf = tt; while (buf >= 3) buf -= 3;
            const char* pb = s.pB + buf * 4096;
            f32x4 f0 = *(const f32x4*)(pb + s.xoff0);
            f32x4 f1 = *(const f32x4*)(pb + s.xoff1);
            f32x4 f2 = *(const f32x4*)(pb + 2048 + s.xoff0);
            f32x4 f3 = *(const f32x4*)(pb + 2048 + s.xoff1);
            __builtin_amdgcn_s_setprio(1);
            __builtin_amdgcn_s_setprio(0);
            #pragma unroll
            for (int j = 0; j < 4; ++j) {
                TOP3_INS(f0[j], t0[0][j], t1[0][j], t2[0][j]);
                TOP3_INS(f1[j], t0[1][j], t1[1][j], t2[1][j]);
                TOP3_INS(f2[j], t0[0][j], t1[0][j], t2[0][j]);
                TOP3_INS(f3[j], t0[1][j], t1[1][j], t2[1][j]);
            }
        }
    }
    #pragma unroll
    for (int r = 0; r < 2; ++r)
        #pragma unroll
        for (int j = 0; j < 4; ++j) {
            keep(t0[r][j]); keep(t1[r][j]); keep(t2[r][j]);
        }
    if (threadIdx.x == 0)
        scratch[blockIdx.x + NBLK_X * blockIdx.y] = 1.0f;
}

// D: no-TOP3 — full rhythm + MFMA; 1-op sum accumulation instead of TOP3.
__global__ __launch_bounds__(256, 4) void abl_notop3_kernel(
    const __bf16* __restrict__ qb, const __bf16* __restrict__ sb,
    float* __restrict__ scratch) {
    __shared__ char smem[3][4096];
    Setup s = make_setup(qb, sb, (char*)smem);
    const int QNT = ABL_QNT(s);
    float sum[2][4];
    #pragma unroll
    for (int r = 0; r < 2; ++r)
        #pragma unroll
        for (int j = 0; j < 4; ++j) sum[r][j] = 0.f;
    const f32x4 z = {0.f, 0.f, 0.f, 0.f};
    #pragma unroll 1
    for (int rep = 0; rep < 4; ++rep) {
        gload_lds16(s.stage_src, (char*)smem + s.sdst);
        gload_lds16(s.stage_src + TILE_BYTES, (char*)smem + 4096 + s.sdst);
        #pragma unroll 1
        for (int tt = 0; tt < QNT; ++tt) {
            if (tt < QNT - 1) asm volatile("s_waitcnt vmcnt(1)" ::: "memory");
            else              asm volatile("s_waitcnt vmcnt(0)" ::: "memory");
            __builtin_amdgcn_s_barrier();
            if (tt + 2 < QNT) {
                int pbuf = tt + 2; while (pbuf >= 3) pbuf -= 3;
                gload_lds16(s.stage_src + (tt + 2) * TILE_BYTES,
                            (char*)smem + pbuf * 4096 + s.sdst);
            }
            int buf = tt; while (buf >= 3) buf -= 3;
            const char* pb = s.pB + buf * 4096;
            bf16x8 b0 = *(const bf16x8*)(pb + s.xoff0);
            bf16x8 b1 = *(const bf16x8*)(pb + s.xoff1);
            bf16x8 b2 = *(const bf16x8*)(pb + 2048 + s.xoff0);
            bf16x8 b3 = *(const bf16x8*)(pb + 2048 + s.xoff1);
            f32x4 acc0, acc1, acc2, acc3;
            __builtin_amdgcn_s_setprio(1);
            acc0 = MFMA16(s.a0[0], b0, z); acc0 = MFMA16(s.a1[0], b1, acc0);
            acc1 = MFMA16(s.a0[1], b0, z); acc1 = MFMA16(s.a1[1], b1, acc1);
            acc2 = MFMA16(s.a0[0], b2, z); acc2 = MFMA16(s.a1[0], b3, acc2);
            acc3 = MFMA16(s.a0[1], b2, z); acc3 = MFMA16(s.a1[1], b3, acc3);
            __builtin_amdgcn_s_setprio(0);
            #pragma unroll
            for (int j = 0; j < 4; ++j) {
                sum[0][j] += acc0[j] + acc2[j];
                sum[1][j] += acc1[j] + acc3[j];
            }
        }
    }
    #pragma unroll
    for (int r = 0; r < 2; ++r)
        #pragma unroll
        for (int j = 0; j < 4; ++j) keep(sum[r][j]);
    if (threadIdx.x == 0)
        scratch[blockIdx.x + NBLK_X * blockIdx.y] = 1.0f;
}

// ---------------------------------------------------------------------------
// Kernel 3: merge quarter partial top-3s, sigmoid, reduce over 441 locations.
// ---------------------------------------------------------------------------
__global__ __launch_bounds__(64) void merge_reduce_kernel(
    const float* __restrict__ part, float* __restrict__ out) {
    int bl = blockIdx.x;
    int b = bl / CLASSES;
    int l = bl % CLASSES;
    int lane = threadIdx.x;
    float acc = 0.f;
    for (int p = lane; p < HW; p += 64) {
        int row = b * HW + p;
        const float* pp = part + (size_t)(row * CLASSES + l) * (QUARTERS * 3);
        float u0 = pp[0], u1 = pp[1], u2 = pp[2];
        TRIPLE_MERGE(u0, u1, u2, pp[3], pp[4],  pp[5]);
        TRIPLE_MERGE(u0, u1, u2, pp[6], pp[7],  pp[8]);
        TRIPLE_MERGE(u0, u1, u2, pp[9], pp[10], pp[11]);
        acc += 1.f / (1.f + __expf(-u0))
             + 1.f / (1.f + __expf(-u1))
             + 1.f / (1.f + __expf(-u2));
    }
    #pragma unroll
    for (int off = 32; off; off >>= 1) acc += __shfl_xor(acc, off, 64);
    if (lane == 0) out[bl] = acc;
}

// ---------------------------------------------------------------------------
extern "C" void kernel_launch(void* const* d_in, const int* in_sizes, int n_in,
                              void* d_out, int out_size, void* d_ws, size_t ws_size,
                              hipStream_t stream) {
    const float* anchor  = (const float*)d_in[0];
    const float* support = (const float*)d_in[1];
    // d_in[2]=av_num(1), d_in[3]=sav_num(1) -- fixed by setup, ignored.

    // ws: sb bf16[5*2304*64] | qb bf16[NROWS*64] | part f32[NROWS*5*4*3]
    //     | abl scratch (4 x 2220 f32 token regions)
    __bf16* sb = (__bf16*)d_ws;
    __bf16* qb = sb + (size_t)CLASSES * PER_CLS_PAD * C_DIM;
    float* part = (float*)(qb + (size_t)NROWS * C_DIM);
    float* abl  = part + (size_t)NROWS * CLASSES * QUARTERS * 3;

    {
        int total = MSUP + NROWS + CLASSES * NPAD;
        dim3 g((total + 255) / 256);
        norm_rows_kernel<<<g, 256, 0, stream>>>(anchor, support, qb, sb);
    }
    dim3 g(NBLK_X, CLASSES * QUARTERS);
    knn_mfma_kernel<<<g, 256, 0, stream>>>(qb, sb, part);
    // --- diagnostic ablations (x4 repeat each; d_out unaffected) ---
    abl_skel_kernel  <<<g, 256, 0, stream>>>(qb, sb, abl);
    abl_nosync_kernel<<<g, 256, 0, stream>>>(qb, sb, abl + 2220);
    abl_nomfma_kernel<<<g, 256, 0, stream>>>(qb, sb, abl + 4440);
    abl_notop3_kernel<<<g, 256, 0, stream>>>(qb, sb, abl + 6660);
    {
        dim3 gm(B_ANCH * CLASSES);
        merge_reduce_kernel<<<gm, 64, 0, stream>>>(part, (float*)d_out);
    }
}

// Round 17
// 56.770 us; speedup vs baseline: 6.2675x; 6.2675x over previous
//
#include <hip/hip_runtime.h>
#include <hip/hip_bf16.h>
#include <math.h>

// Problem constants (from setup_inputs / reference)
#define CLASSES     5
#define C_DIM       64
#define HW          441            // 21*21
#define B_ANCH      32
#define NSUP        25             // L*S support images
#define NROWS       (B_ANCH*HW)    // 14112 query rows
#define MSUP        (NSUP*HW)      // 11025 support descriptors
#define PER_CLS     (MSUP/CLASSES) // 2205 per class
#define TILE_COLS   32
#define ROW_BYTES   (C_DIM*2)      // 128 B per bf16 descriptor row
#define TILE_BYTES  (TILE_COLS*ROW_BYTES)   // 4 KB
#define PER_CLS_PAD 2304           // 72 tiles of 32
#define NPAD        (PER_CLS_PAD - PER_CLS) // 99 zero-filled pad rows/class
#define QUARTERS    4              // column splits per class (grid.y = 5*4)
#define TILES_PER_Q 18             // 18 tiles of 32 cols = 576 cols/quarter
#define ROWS_PER_BLK 256           // 4 waves x 64 rows (M_rep=4)
#define NBLK_X      ((NROWS + ROWS_PER_BLK - 1) / ROWS_PER_BLK)  // 56

#define NEG_INF  (-1e30f)

typedef __bf16 bf16x8 __attribute__((ext_vector_type(8)));
typedef float  f32x4  __attribute__((ext_vector_type(4)));

// top-3 insert via med3: 3 independent ops; t0 >= t1 >= t2 invariant.
#define TOP3_INS(v, t0, t1, t2) do {                              \
    float _v = (v);                                               \
    float _n0 = fmaxf(_v, (t0));                                  \
    float _n1 = __builtin_amdgcn_fmed3f(_v, (t0), (t1));          \
    float _n2 = __builtin_amdgcn_fmed3f(_v, (t1), (t2));          \
    (t0) = _n0; (t1) = _n1; (t2) = _n2; } while (0)

// Merge two SORTED triples (u desc, v desc) -> u = top-3 of union. 6 ops.
// Field-validated rounds 9-16 (absmax 0).
#define TRIPLE_MERGE(u0, u1, u2, v0, v1, v2) do {                 \
    float _A = fminf((u0), (v0));                                 \
    float _B = fmaxf((u1), (v1));                                 \
    float _E = fmaxf((u2), (v2));                                 \
    float _m0 = fmaxf((u0), (v0));                                \
    float _m1 = __builtin_amdgcn_fmed3f((u0), (v0), _B);          \
    float _m2 = __builtin_amdgcn_fmed3f(_A, _B, _E);              \
    (u0) = _m0; (u1) = _m1; (u2) = _m2; } while (0)

typedef __attribute__((address_space(1))) const void g_void;
typedef __attribute__((address_space(3))) void l_void;
__device__ __forceinline__ void gload_lds16(const void* g, void* l) {
    __builtin_amdgcn_global_load_lds((g_void*)g, (l_void*)l, 16, 0, 0);
}
#define MFMA16(A, B, C) __builtin_amdgcn_mfma_f32_16x16x32_bf16((A), (B), (C), 0, 0, 0)

// ---------------------------------------------------------------------------
// Kernel 1: L2-normalize all rows (support + anchor) into row-major bf16.
// Support -> sb with per-class row stride PER_CLS_PAD; pad rows zero-filled.
// ---------------------------------------------------------------------------
__global__ __launch_bounds__(256) void norm_rows_kernel(
    const float* __restrict__ anchor, const float* __restrict__ support,
    __bf16* __restrict__ qb, __bf16* __restrict__ sb) {
    int r = blockIdx.x * 256 + threadIdx.x;
    const int total_main = MSUP + NROWS;
    if (r >= total_main) {
        int i = r - total_main;                    // pad-row zero fill
        if (i < CLASSES * NPAD) {
            int cls = i / NPAD, ix = PER_CLS + i % NPAD;
            __bf16* op = sb + ((size_t)cls * PER_CLS_PAD + ix) * C_DIM;
            bf16x8 z = {};
            #pragma unroll
            for (int c0 = 0; c0 < C_DIM; c0 += 8) *(bf16x8*)(op + c0) = z;
        }
        return;
    }
    bool isSup = r < MSUP;
    int rc = isSup ? r : r - MSUP;
    const float* in = isSup ? support : anchor;
    int img = rc / HW, p = rc % HW;
    const float* base = in + (size_t)img * C_DIM * HW + p;
    float q[C_DIM];
    float ss = 0.f;
    #pragma unroll
    for (int c = 0; c < C_DIM; ++c) { q[c] = base[c * HW]; ss += q[c] * q[c]; }
    float sc = rsqrtf(ss);
    __bf16* op;
    if (isSup) {
        int cls = rc / PER_CLS, ix = rc - cls * PER_CLS;
        op = sb + ((size_t)cls * PER_CLS_PAD + ix) * C_DIM;
    } else {
        op = qb + (size_t)rc * C_DIM;
    }
    #pragma unroll
    for (int c0 = 0; c0 < C_DIM; c0 += 8) {
        bf16x8 v;
        #pragma unroll
        for (int j = 0; j < 8; ++j) v[j] = (__bf16)(q[c0 + j] * sc);
        *(bf16x8*)(op + c0) = v;
    }
}

// ---------------------------------------------------------------------------
// Fully-unrolled GEMM+top3 over one column-quarter (QNT tiles of 32 cols).
// M_rep=4: wave owns 64 rows; each staged B byte feeds 2x the rows of the
// round-15 kernel -> per-CU LDS-pipe traffic halves (the R16 ablation's
// dominant component). Staging identical to R15: contiguous 1KB/wave,
// XOR-swizzled both-sides, 3 buffers, counted vmcnt(1).
// Per tile: {read b0,b1 -> 8 MFMA (s=0) -> read b2,b3 -> TOP3 s=0 ->
// 8 MFMA (s=1) -> TOP3 s=1} — b2/b3 LDS latency hides under s=0's TOP3;
// b regs reused (keeps peak VGPR < 128 / 4-wave cliff).
// TAIL=true: last tile is class cols 2176-2207 (s=0 full, s=1 iff lr<13).
// ---------------------------------------------------------------------------
template<int QNT, bool TAIL>
__device__ __forceinline__ void gemm_quarter(
    const char* stage_src, char* smem_base, const char* pB,
    int xoff0, int xoff1, int stage_dst_off, int lane, int lr,
    const bf16x8 a0[4], const bf16x8 a1[4],
    float t0[4][4], float t1[4][4], float t2[4][4]) {

    auto stage = [&](int buf, int tt) {
        gload_lds16(stage_src + tt * TILE_BYTES,
                    smem_base + buf * 4096 + stage_dst_off);
    };
    const f32x4 z = {0.f, 0.f, 0.f, 0.f};
    stage(0, 0);
    stage(1, 1);
    #pragma unroll
    for (int tt = 0; tt < QNT; ++tt) {
        if (tt < QNT - 1) asm volatile("s_waitcnt vmcnt(1)" ::: "memory");
        else              asm volatile("s_waitcnt vmcnt(0)" ::: "memory");
        __builtin_amdgcn_s_barrier();
        if (tt + 2 < QNT) stage((tt + 2) % 3, tt + 2);
        const int buf = tt % 3;
        const bool tail = TAIL && (tt == QNT - 1);
        const char* pb = pB + buf * 4096;

        // s = 0 column-group (always valid)
        bf16x8 b0 = *(const bf16x8*)(pb + xoff0);
        bf16x8 b1 = *(const bf16x8*)(pb + xoff1);
        f32x4 acc[4];
        __builtin_amdgcn_s_setprio(1);
        #pragma unroll
        for (int r = 0; r < 4; ++r) {
            acc[r] = MFMA16(a0[r], b0, z);
            acc[r] = MFMA16(a1[r], b1, acc[r]);
        }
        __builtin_amdgcn_s_setprio(0);
        // issue s=1 reads now: latency hides under s=0's TOP3 stream
        bf16x8 b2 = *(const bf16x8*)(pb + 2048 + xoff0);
        bf16x8 b3 = *(const bf16x8*)(pb + 2048 + xoff1);
        #pragma unroll
        for (int r = 0; r < 4; ++r)
            #pragma unroll
            for (int j = 0; j < 4; ++j)
                TOP3_INS(acc[r][j], t0[r][j], t1[r][j], t2[r][j]);

        // s = 1 column-group (tail: valid iff lr < 13)
        f32x4 acd[4];
        __builtin_amdgcn_s_setprio(1);
        #pragma unroll
        for (int r = 0; r < 4; ++r) {
            acd[r] = MFMA16(a0[r], b2, z);
            acd[r] = MFMA16(a1[r], b3, acd[r]);
        }
        __builtin_amdgcn_s_setprio(0);
        if (!tail) {
            #pragma unroll
            for (int r = 0; r < 4; ++r)
                #pragma unroll
                for (int j = 0; j < 4; ++j)
                    TOP3_INS(acd[r][j], t0[r][j], t1[r][j], t2[r][j]);
        } else {
            bool valid = lr < 13;     // SELECT mask: pad rows stay out
            #pragma unroll
            for (int r = 0; r < 4; ++r)
                #pragma unroll
                for (int j = 0; j < 4; ++j) {
                    float v = valid ? acd[r][j] : NEG_INF;
                    TOP3_INS(v, t0[r][j], t1[r][j], t2[r][j]);
                }
        }
    }
}

// ---------------------------------------------------------------------------
// Kernel 2: MFMA GEMM + partial top-3 per (row, class, quarter).
// Grid (56, 20), block 256 = 4 waves; wave owns 64 rows (M_rep=4).
// LDS 12 KB (3 x 4KB); contiguous staging + XOR-swizzled LDS reads.
// __launch_bounds__(256,3): ~119 VGPR needed — stay clear of the forced-
// spill cliff (R11 lesson); occupancy is not the lever here (R12 lesson).
// A/B frag: row/col = lane&15, k = (lane>>4)*8+[0..7].
// C/D: col = lane&15, row = (lane>>4)*4 + reg.   (validated rounds 2-16)
// ---------------------------------------------------------------------------
__global__ __launch_bounds__(256, 3) void knn_mfma_kernel(
    const __bf16* __restrict__ qb, const __bf16* __restrict__ sb,
    float* __restrict__ part) {
    __shared__ char smem[3][4096];   // 12 KB

    int lane = threadIdx.x & 63;
    int w    = threadIdx.x >> 6;           // 0..3
    int lr   = lane & 15;
    int kg   = lane >> 4;
    int cls  = blockIdx.y >> 2;
    int q    = blockIdx.y & 3;
    int rowbase = blockIdx.x * ROWS_PER_BLK + w * 64;

    bf16x8 a0[4], a1[4];
    #pragma unroll
    for (int r = 0; r < 4; ++r) {
        int arow = rowbase + r * 16 + lr;
        int arc  = arow < NROWS ? arow : NROWS - 1;
        const bf16x8* qrow = (const bf16x8*)(qb + (size_t)arc * C_DIM);
        a0[r] = qrow[kg];
        a1[r] = qrow[4 + kg];
    }

    float t0[4][4], t1[4][4], t2[4][4];
    #pragma unroll
    for (int r = 0; r < 4; ++r)
        #pragma unroll
        for (int j = 0; j < 4; ++j) {
            t0[r][j] = NEG_INF; t1[r][j] = NEG_INF; t2[r][j] = NEG_INF;
        }

    // ---- contiguous-stage addressing (validated R15) ----------------------
    int srow = lane >> 3;                       // 0..7 (row within 1KB chunk)
    int sgrn = (lane & 7) ^ (srow & 7);         // XOR-permuted granule
    int srcSwz = srow * 128 + sgrn * 16;        // contiguous 1KB footprint
    const char* qbase = (const char*)sb
        + (size_t)cls * PER_CLS_PAD * ROW_BYTES
        + (size_t)q * TILES_PER_Q * TILE_BYTES;
    const char* stage_src = qbase + w * 1024 + srcSwz;
    // ---- swizzled B-fragment read addressing ------------------------------
    int xoff0 = (((lr & 7) ^ kg) << 4);         // h=0
    int xoff1 = xoff0 ^ 0x40;                   // h=1 (flip bit 6)
    const char* pB = (const char*)smem + lr * 128;

    if (q == 3)   // tiles 54..68 valid (69..71 all-pad skipped), tail masked
        gemm_quarter<15, true >(stage_src, (char*)smem, pB, xoff0, xoff1,
                                w * 1024, lane, lr, a0, a1, t0, t1, t2);
    else
        gemm_quarter<18, false>(stage_src, (char*)smem, pB, xoff0, xoff1,
                                w * 1024, lane, lr, a0, a1, t0, t1, t2);

    // Merge top-3 across the 16 column-lanes per row (sorted-triple butterfly)
    #pragma unroll
    for (int r = 0; r < 4; ++r) {
        #pragma unroll
        for (int j = 0; j < 4; ++j) {
            float u0 = t0[r][j], u1 = t1[r][j], u2 = t2[r][j];
            #pragma unroll
            for (int off = 1; off < 16; off <<= 1) {
                float v0 = __shfl_xor(u0, off, 64);
                float v1 = __shfl_xor(u1, off, 64);
                float v2 = __shfl_xor(u2, off, 64);
                TRIPLE_MERGE(u0, u1, u2, v0, v1, v2);
            }
            int row = rowbase + r * 16 + kg * 4 + j;
            if (lr == 0 && row < NROWS) {
                float* pp = part +
                    ((size_t)(row * CLASSES + cls) * QUARTERS + q) * 3;
                pp[0] = u0; pp[1] = u1; pp[2] = u2;
            }
        }
    }
}

// ---------------------------------------------------------------------------
// Kernel 3: merge quarter partial top-3s, sigmoid, reduce over 441 locations.
// ---------------------------------------------------------------------------
__global__ __launch_bounds__(64) void merge_reduce_kernel(
    const float* __restrict__ part, float* __restrict__ out) {
    int bl = blockIdx.x;
    int b = bl / CLASSES;
    int l = bl % CLASSES;
    int lane = threadIdx.x;
    float acc = 0.f;
    for (int p = lane; p < HW; p += 64) {
        int row = b * HW + p;
        const float* pp = part + (size_t)(row * CLASSES + l) * (QUARTERS * 3);
        float u0 = pp[0], u1 = pp[1], u2 = pp[2];
        TRIPLE_MERGE(u0, u1, u2, pp[3], pp[4],  pp[5]);
        TRIPLE_MERGE(u0, u1, u2, pp[6], pp[7],  pp[8]);
        TRIPLE_MERGE(u0, u1, u2, pp[9], pp[10], pp[11]);
        acc += 1.f / (1.f + __expf(-u0))
             + 1.f / (1.f + __expf(-u1))
             + 1.f / (1.f + __expf(-u2));
    }
    #pragma unroll
    for (int off = 32; off; off >>= 1) acc += __shfl_xor(acc, off, 64);
    if (lane == 0) out[bl] = acc;
}

// ---------------------------------------------------------------------------
extern "C" void kernel_launch(void* const* d_in, const int* in_sizes, int n_in,
                              void* d_out, int out_size, void* d_ws, size_t ws_size,
                              hipStream_t stream) {
    const float* anchor  = (const float*)d_in[0];
    const float* support = (const float*)d_in[1];
    // d_in[2]=av_num(1), d_in[3]=sav_num(1) -- fixed by setup, ignored.

    // ws: sb bf16[5*2304*64] | qb bf16[NROWS*64] | part f32[NROWS*5*4*3]
    __bf16* sb = (__bf16*)d_ws;
    __bf16* qb = sb + (size_t)CLASSES * PER_CLS_PAD * C_DIM;
    float* part = (float*)(qb + (size_t)NROWS * C_DIM);

    {
        int total = MSUP + NROWS + CLASSES * NPAD;
        dim3 g((total + 255) / 256);
        norm_rows_kernel<<<g, 256, 0, stream>>>(anchor, support, qb, sb);
    }
    {
        dim3 g(NBLK_X, CLASSES * QUARTERS);
        knn_mfma_kernel<<<g, 256, 0, stream>>>(qb, sb, part);
    }
    {
        dim3 gm(B_ANCH * CLASSES);
        merge_reduce_kernel<<<gm, 64, 0, stream>>>(part, (float*)d_out);
    }
}

// Round 18
// 53.516 us; speedup vs baseline: 6.6487x; 1.0608x over previous
//
#include <hip/hip_runtime.h>
#include <hip/hip_bf16.h>
#include <math.h>

// Problem constants (from setup_inputs / reference)
#define CLASSES     5
#define C_DIM       64
#define HW          441            // 21*21
#define B_ANCH      32
#define NSUP        25             // L*S support images
#define NROWS       (B_ANCH*HW)    // 14112 query rows
#define MSUP        (NSUP*HW)      // 11025 support descriptors
#define PER_CLS     (MSUP/CLASSES) // 2205 per class
#define TILE_COLS   32
#define ROW_BYTES   (C_DIM*2)      // 128 B per bf16 descriptor row
#define TILE_BYTES  (TILE_COLS*ROW_BYTES)   // 4 KB
#define PER_CLS_PAD 2304           // 72 tiles of 32
#define NPAD        (PER_CLS_PAD - PER_CLS) // 99 zero-filled pad rows/class
#define QUARTERS    4              // column splits per class (grid.y = 5*4)
#define TILES_PER_Q 18             // 18 tiles of 32 cols = 576 cols/quarter
#define ROWS_PER_BLK 128           // 4 waves x 32 rows (M_rep=2)
#define NBLK_X      ((NROWS + ROWS_PER_BLK - 1) / ROWS_PER_BLK)  // 111

#define NEG_INF  (-1e30f)

typedef __bf16 bf16x8 __attribute__((ext_vector_type(8)));
typedef float  f32x4  __attribute__((ext_vector_type(4)));

// top-3 insert via med3: 3 independent ops; t0 >= t1 >= t2 invariant.
#define TOP3_INS(v, t0, t1, t2) do {                              \
    float _v = (v);                                               \
    float _n0 = fmaxf(_v, (t0));                                  \
    float _n1 = __builtin_amdgcn_fmed3f(_v, (t0), (t1));          \
    float _n2 = __builtin_amdgcn_fmed3f(_v, (t1), (t2));          \
    (t0) = _n0; (t1) = _n1; (t2) = _n2; } while (0)

// Merge two SORTED triples (u desc, v desc) -> u = top-3 of union. 6 ops.
// Field-validated rounds 9-17 (absmax 0).
#define TRIPLE_MERGE(u0, u1, u2, v0, v1, v2) do {                 \
    float _A = fminf((u0), (v0));                                 \
    float _B = fmaxf((u1), (v1));                                 \
    float _E = fmaxf((u2), (v2));                                 \
    float _m0 = fmaxf((u0), (v0));                                \
    float _m1 = __builtin_amdgcn_fmed3f((u0), (v0), _B);          \
    float _m2 = __builtin_amdgcn_fmed3f(_A, _B, _E);              \
    (u0) = _m0; (u1) = _m1; (u2) = _m2; } while (0)

typedef __attribute__((address_space(1))) const void g_void;
typedef __attribute__((address_space(3))) void l_void;
__device__ __forceinline__ void gload_lds16(const void* g, void* l) {
    __builtin_amdgcn_global_load_lds((g_void*)g, (l_void*)l, 16, 0, 0);
}
#define MFMA16(A, B, C) __builtin_amdgcn_mfma_f32_16x16x32_bf16((A), (B), (C), 0, 0, 0)

// ---------------------------------------------------------------------------
// Kernel 1: L2-normalize all rows (support + anchor) into row-major bf16.
// Support -> sb with per-class row stride PER_CLS_PAD; pad rows zero-filled.
// ---------------------------------------------------------------------------
__global__ __launch_bounds__(256) void norm_rows_kernel(
    const float* __restrict__ anchor, const float* __restrict__ support,
    __bf16* __restrict__ qb, __bf16* __restrict__ sb) {
    int r = blockIdx.x * 256 + threadIdx.x;
    const int total_main = MSUP + NROWS;
    if (r >= total_main) {
        int i = r - total_main;                    // pad-row zero fill
        if (i < CLASSES * NPAD) {
            int cls = i / NPAD, ix = PER_CLS + i % NPAD;
            __bf16* op = sb + ((size_t)cls * PER_CLS_PAD + ix) * C_DIM;
            bf16x8 z = {};
            #pragma unroll
            for (int c0 = 0; c0 < C_DIM; c0 += 8) *(bf16x8*)(op + c0) = z;
        }
        return;
    }
    bool isSup = r < MSUP;
    int rc = isSup ? r : r - MSUP;
    const float* in = isSup ? support : anchor;
    int img = rc / HW, p = rc % HW;
    const float* base = in + (size_t)img * C_DIM * HW + p;
    float q[C_DIM];
    float ss = 0.f;
    #pragma unroll
    for (int c = 0; c < C_DIM; ++c) { q[c] = base[c * HW]; ss += q[c] * q[c]; }
    float sc = rsqrtf(ss);
    __bf16* op;
    if (isSup) {
        int cls = rc / PER_CLS, ix = rc - cls * PER_CLS;
        op = sb + ((size_t)cls * PER_CLS_PAD + ix) * C_DIM;
    } else {
        op = qb + (size_t)rc * C_DIM;
    }
    #pragma unroll
    for (int c0 = 0; c0 < C_DIM; c0 += 8) {
        bf16x8 v;
        #pragma unroll
        for (int j = 0; j < 8; ++j) v[j] = (__bf16)(q[c0 + j] * sc);
        *(bf16x8*)(op + c0) = v;
    }
}

// ---------------------------------------------------------------------------
// PIPELINED GEMM+top3 over one column-quarter (QNT tiles of 32 cols).
// The new lever vs R15: CROSS-TILE REGISTER PREFETCH. Per iteration t:
//   vmcnt + barrier   (tile t+1's staging complete block-wide)
//   ds_read b_next <- tile t+1          (latency hides under this iter)
//   stage tile t+3                      (counted vmcnt keeps it in flight)
//   MFMA on b_cur (tile t, read LAST iteration -> no lgkm stall)
//   TOP3 on accs
// 4 LDS buffers (16 KB); vmcnt(1) until t=QNT-3, vmcnt(0) at t=QNT-2
// (FIFO-oldest rule: ensures stage(t+1) has landed in both cases); last
// iteration needs no sync at all. bA/bB named register sets, full unroll.
// TAIL=true: last tile is class cols 2176-2207 (s=0 full, s=1 iff lr<13).
// ---------------------------------------------------------------------------
template<int QNT, bool TAIL>
__device__ __forceinline__ void gemm_quarter(
    const char* stage_src, char* smem_base, const char* pB,
    int xoff0, int xoff1, int stage_dst_off, int lane, int lr,
    const bf16x8 a0[2], const bf16x8 a1[2],
    float t0[2][4], float t1[2][4], float t2[2][4]) {

    auto stage = [&](int buf, int tt) {
        gload_lds16(stage_src + tt * TILE_BYTES,
                    smem_base + buf * 4096 + stage_dst_off);
    };
    auto ldsread = [&](int buf, bf16x8 b[4]) {
        const char* pb = pB + buf * 4096;
        b[0] = *(const bf16x8*)(pb + xoff0);
        b[1] = *(const bf16x8*)(pb + xoff1);
        b[2] = *(const bf16x8*)(pb + 2048 + xoff0);
        b[3] = *(const bf16x8*)(pb + 2048 + xoff1);
    };
    const f32x4 z = {0.f, 0.f, 0.f, 0.f};

    // prologue: stage 0,1; wait tile 0; read tile 0 into bA; stage 2
    stage(0, 0);
    stage(1, 1);
    asm volatile("s_waitcnt vmcnt(1)" ::: "memory");
    __builtin_amdgcn_s_barrier();
    bf16x8 bA[4], bB[4];
    ldsread(0, bA);
    stage(2, 2);

    #pragma unroll
    for (int t = 0; t < QNT; ++t) {
        if (t < QNT - 1) {
            // ensure tile t+1 staged block-wide (outstanding stages beyond
            // t+1: one if t+2 <= QNT-1, else zero)
            if (t <= QNT - 3) asm volatile("s_waitcnt vmcnt(1)" ::: "memory");
            else              asm volatile("s_waitcnt vmcnt(0)" ::: "memory");
            __builtin_amdgcn_s_barrier();
        }
        // prefetch tile t+1's fragments into the alternate register set
        if (t < QNT - 1) {
            if (t & 1) ldsread((t + 1) % 4, bA);
            else       ldsread((t + 1) % 4, bB);
        }
        if (t + 3 < QNT) stage((t + 3) % 4, t + 3);

        const bf16x8* bc = (t & 1) ? bB : bA;   // compile-time under unroll
        f32x4 acc0, acc1, acc2, acc3;
        __builtin_amdgcn_s_setprio(1);
        acc0 = MFMA16(a0[0], bc[0], z); acc0 = MFMA16(a1[0], bc[1], acc0);
        acc1 = MFMA16(a0[1], bc[0], z); acc1 = MFMA16(a1[1], bc[1], acc1);
        acc2 = MFMA16(a0[0], bc[2], z); acc2 = MFMA16(a1[0], bc[3], acc2);
        acc3 = MFMA16(a0[1], bc[2], z); acc3 = MFMA16(a1[1], bc[3], acc3);
        __builtin_amdgcn_s_setprio(0);

        const bool tail = TAIL && (t == QNT - 1);
        if (!tail) {
            #pragma unroll
            for (int j = 0; j < 4; ++j) {
                TOP3_INS(acc0[j], t0[0][j], t1[0][j], t2[0][j]);
                TOP3_INS(acc1[j], t0[1][j], t1[1][j], t2[1][j]);
                TOP3_INS(acc2[j], t0[0][j], t1[0][j], t2[0][j]);
                TOP3_INS(acc3[j], t0[1][j], t1[1][j], t2[1][j]);
            }
        } else {
            // tail tile: s=0 (acc0/acc1) full; s=1 (acc2/acc3) iff lr<13
            bool valid = lr < 13;     // SELECT mask: pad rows stay out
            #pragma unroll
            for (int j = 0; j < 4; ++j) {
                TOP3_INS(acc0[j], t0[0][j], t1[0][j], t2[0][j]);
                TOP3_INS(acc1[j], t0[1][j], t1[1][j], t2[1][j]);
                float v2 = valid ? acc2[j] : NEG_INF;
                float v3 = valid ? acc3[j] : NEG_INF;
                TOP3_INS(v2, t0[0][j], t1[0][j], t2[0][j]);
                TOP3_INS(v3, t0[1][j], t1[1][j], t2[1][j]);
            }
        }
    }
}

// ---------------------------------------------------------------------------
// Kernel 2: MFMA GEMM + partial top-3 per (row, class, quarter).
// Grid (111, 20), block 256 = 4 waves; wave owns 32 rows (M_rep=2).
// LDS 16 KB (4 x 4KB); contiguous staging + XOR-swizzled LDS reads (R15).
// A/B frag: row/col = lane&15, k = (lane>>4)*8+[0..7].
// C/D: col = lane&15, row = (lane>>4)*4 + reg.   (validated rounds 2-17)
// ---------------------------------------------------------------------------
__global__ __launch_bounds__(256, 4) void knn_mfma_kernel(
    const __bf16* __restrict__ qb, const __bf16* __restrict__ sb,
    float* __restrict__ part) {
    __shared__ char smem[4][4096];   // 16 KB

    int lane = threadIdx.x & 63;
    int w    = threadIdx.x >> 6;           // 0..3
    int lr   = lane & 15;
    int kg   = lane >> 4;
    int cls  = blockIdx.y >> 2;
    int q    = blockIdx.y & 3;
    int rowbase = blockIdx.x * ROWS_PER_BLK + w * 32;

    bf16x8 a0[2], a1[2];
    #pragma unroll
    for (int r = 0; r < 2; ++r) {
        int arow = rowbase + r * 16 + lr;
        int arc  = arow < NROWS ? arow : NROWS - 1;
        const bf16x8* qrow = (const bf16x8*)(qb + (size_t)arc * C_DIM);
        a0[r] = qrow[kg];
        a1[r] = qrow[4 + kg];
    }

    float t0[2][4], t1[2][4], t2[2][4];
    #pragma unroll
    for (int r = 0; r < 2; ++r)
        #pragma unroll
        for (int j = 0; j < 4; ++j) {
            t0[r][j] = NEG_INF; t1[r][j] = NEG_INF; t2[r][j] = NEG_INF;
        }

    // ---- contiguous-stage addressing (validated R15) ----------------------
    int srow = lane >> 3;                       // 0..7 (row within 1KB chunk)
    int sgrn = (lane & 7) ^ (srow & 7);         // XOR-permuted granule
    int srcSwz = srow * 128 + sgrn * 16;        // contiguous 1KB footprint
    const char* qbase = (const char*)sb
        + (size_t)cls * PER_CLS_PAD * ROW_BYTES
        + (size_t)q * TILES_PER_Q * TILE_BYTES;
    const char* stage_src = qbase + w * 1024 + srcSwz;
    // ---- swizzled B-fragment read addressing ------------------------------
    int xoff0 = (((lr & 7) ^ kg) << 4);         // h=0
    int xoff1 = xoff0 ^ 0x40;                   // h=1 (flip bit 6)
    const char* pB = (const char*)smem + lr * 128;

    if (q == 3)   // tiles 54..68 valid (69..71 all-pad skipped), tail masked
        gemm_quarter<15, true >(stage_src, (char*)smem, pB, xoff0, xoff1,
                                w * 1024, lane, lr, a0, a1, t0, t1, t2);
    else
        gemm_quarter<18, false>(stage_src, (char*)smem, pB, xoff0, xoff1,
                                w * 1024, lane, lr, a0, a1, t0, t1, t2);

    // Merge top-3 across the 16 column-lanes per row (sorted-triple butterfly)
    #pragma unroll
    for (int r = 0; r < 2; ++r) {
        #pragma unroll
        for (int j = 0; j < 4; ++j) {
            float u0 = t0[r][j], u1 = t1[r][j], u2 = t2[r][j];
            #pragma unroll
            for (int off = 1; off < 16; off <<= 1) {
                float v0 = __shfl_xor(u0, off, 64);
                float v1 = __shfl_xor(u1, off, 64);
                float v2 = __shfl_xor(u2, off, 64);
                TRIPLE_MERGE(u0, u1, u2, v0, v1, v2);
            }
            int row = rowbase + r * 16 + kg * 4 + j;
            if (lr == 0 && row < NROWS) {
                float* pp = part +
                    ((size_t)(row * CLASSES + cls) * QUARTERS + q) * 3;
                pp[0] = u0; pp[1] = u1; pp[2] = u2;
            }
        }
    }
}

// ---------------------------------------------------------------------------
// Kernel 3: merge quarter partial top-3s, sigmoid, reduce over 441 locations.
// ---------------------------------------------------------------------------
__global__ __launch_bounds__(64) void merge_reduce_kernel(
    const float* __restrict__ part, float* __restrict__ out) {
    int bl = blockIdx.x;
    int b = bl / CLASSES;
    int l = bl % CLASSES;
    int lane = threadIdx.x;
    float acc = 0.f;
    for (int p = lane; p < HW; p += 64) {
        int row = b * HW + p;
        const float* pp = part + (size_t)(row * CLASSES + l) * (QUARTERS * 3);
        float u0 = pp[0], u1 = pp[1], u2 = pp[2];
        TRIPLE_MERGE(u0, u1, u2, pp[3], pp[4],  pp[5]);
        TRIPLE_MERGE(u0, u1, u2, pp[6], pp[7],  pp[8]);
        TRIPLE_MERGE(u0, u1, u2, pp[9], pp[10], pp[11]);
        acc += 1.f / (1.f + __expf(-u0))
             + 1.f / (1.f + __expf(-u1))
             + 1.f / (1.f + __expf(-u2));
    }
    #pragma unroll
    for (int off = 32; off; off >>= 1) acc += __shfl_xor(acc, off, 64);
    if (lane == 0) out[bl] = acc;
}

// ---------------------------------------------------------------------------
extern "C" void kernel_launch(void* const* d_in, const int* in_sizes, int n_in,
                              void* d_out, int out_size, void* d_ws, size_t ws_size,
                              hipStream_t stream) {
    const float* anchor  = (const float*)d_in[0];
    const float* support = (const float*)d_in[1];
    // d_in[2]=av_num(1), d_in[3]=sav_num(1) -- fixed by setup, ignored.

    // ws: sb bf16[5*2304*64] | qb bf16[NROWS*64] | part f32[NROWS*5*4*3]
    __bf16* sb = (__bf16*)d_ws;
    __bf16* qb = sb + (size_t)CLASSES * PER_CLS_PAD * C_DIM;
    float* part = (float*)(qb + (size_t)NROWS * C_DIM);

    {
        int total = MSUP + NROWS + CLASSES * NPAD;
        dim3 g((total + 255) / 256);
        norm_rows_kernel<<<g, 256, 0, stream>>>(anchor, support, qb, sb);
    }
    {
        dim3 g(NBLK_X, CLASSES * QUARTERS);
        knn_mfma_kernel<<<g, 256, 0, stream>>>(qb, sb, part);
    }
    {
        dim3 gm(B_ANCH * CLASSES);
        merge_reduce_kernel<<<gm, 64, 0, stream>>>(part, (float*)d_out);
    }
}